// Round 2
// baseline (5012.656 us; speedup 1.0000x reference)
//
#include <hip/hip_runtime.h>
#include <math.h>

// Problem constants (fixed by the reference)
constexpr int N_ = 50000;   // nodes
constexpr int E_ = 600000;  // edges per relation
constexpr int F_ = 256;     // feature dim
constexpr int H_ = 128;     // hidden dim
constexpr int Q_ = 64;      // query dim (== one wave)
constexpr int R_ = 2;       // relations
constexpr int L_ = 2;       // conv depth

#define MODE_STORE 0
#define MODE_TANH  1
#define MODE_ACC   2

// ---------------------------------------------------------------------------
// Tiled f32 GEMM: C[M x 64*gridDim.y] = A (M x K) * B
//   BT=true : C[n,j] = sum_k A[n,k] * B[j*ldb + k]   (B^T, row-major B)
//   BT=false: C[n,j] = sum_k A[n,k] * B[k*ldb + j]
// rowscale (optional): multiply row n of the result by rowscale[n]
// Tile: 64x64, BK=16, 256 threads, 4x4 outputs/thread.
// ---------------------------------------------------------------------------
template <bool BT>
__global__ __launch_bounds__(256) void gemm_kernel(
    const float* __restrict__ A, int lda,
    const float* __restrict__ B, int ldb,
    float* __restrict__ C, int ldc,
    int M, int K,
    const float* __restrict__ rowscale, int mode)
{
    __shared__ __align__(16) float As[16][68];
    __shared__ __align__(16) float Bs[16][68];

    const int row0 = blockIdx.x * 64;
    const int col0 = blockIdx.y * 64;
    const int tid  = threadIdx.x;
    const int tm = tid >> 4;
    const int tn = tid & 15;

    float acc[4][4] = {};

    for (int kk = 0; kk < K; kk += 16) {
        {   // A tile: 64 rows x 16 k, one float4 per thread
            const int m  = tid >> 2;
            const int k4 = (tid & 3) * 4;
            const int r  = row0 + m;
            float4 v = make_float4(0.f, 0.f, 0.f, 0.f);
            if (r < M) v = *(const float4*)(A + (size_t)r * lda + kk + k4);
            As[k4 + 0][m] = v.x; As[k4 + 1][m] = v.y;
            As[k4 + 2][m] = v.z; As[k4 + 3][m] = v.w;
        }
        if (BT) {
            const int j  = tid >> 2;
            const int k4 = (tid & 3) * 4;
            float4 v = *(const float4*)(B + (size_t)(col0 + j) * ldb + kk + k4);
            Bs[k4 + 0][j] = v.x; Bs[k4 + 1][j] = v.y;
            Bs[k4 + 2][j] = v.z; Bs[k4 + 3][j] = v.w;
        } else {
            const int k  = tid >> 4;
            const int j4 = (tid & 15) * 4;
            float4 v = *(const float4*)(B + (size_t)(kk + k) * ldb + col0 + j4);
            Bs[k][j4 + 0] = v.x; Bs[k][j4 + 1] = v.y;
            Bs[k][j4 + 2] = v.z; Bs[k][j4 + 3] = v.w;
        }
        __syncthreads();

        #pragma unroll
        for (int k = 0; k < 16; k++) {
            const float4 av = *(const float4*)&As[k][tm * 4];
            const float4 bv = *(const float4*)&Bs[k][tn * 4];
            const float a[4] = {av.x, av.y, av.z, av.w};
            const float b[4] = {bv.x, bv.y, bv.z, bv.w};
            #pragma unroll
            for (int i = 0; i < 4; i++)
                #pragma unroll
                for (int j = 0; j < 4; j++)
                    acc[i][j] += a[i] * b[j];
        }
        __syncthreads();
    }

    #pragma unroll
    for (int i = 0; i < 4; i++) {
        const int r = row0 + tm * 4 + i;
        if (r >= M) continue;
        const float rs = rowscale ? rowscale[r] : 1.0f;
        #pragma unroll
        for (int j = 0; j < 4; j++) {
            const int c = col0 + tn * 4 + j;
            float v = acc[i][j] * rs;
            if (mode == MODE_TANH) v = tanhf(v);
            float* p = C + (size_t)r * ldc + c;
            if (mode == MODE_ACC) *p += v;
            else                  *p = v;
        }
    }
}

// ---------------------------------------------------------------------------
// Fused dual-relation conv GEMM (BT=false, K=H=128, ldb=ldc=128):
//   C0[n,j] = rs0[n] * sum_k A[n,k] * B0[k,j]
//   C1[n,j] = rs1[n] * sum_k A[n,k] * B1[k,j]
// One A-tile staging serves both relations: half the A traffic, half the
// blocks, 32 FMA per 3 LDS float4 reads (vs 16 per 2).
// ---------------------------------------------------------------------------
__global__ __launch_bounds__(256) void gemm_conv_pair(
    const float* __restrict__ A, int lda,
    const float* __restrict__ B0, const float* __restrict__ B1,
    float* __restrict__ C0, float* __restrict__ C1,
    int M, const float* __restrict__ rs0, const float* __restrict__ rs1)
{
    __shared__ __align__(16) float As[16][68];
    __shared__ __align__(16) float B0s[16][68];
    __shared__ __align__(16) float B1s[16][68];

    const int row0 = blockIdx.x * 64;
    const int col0 = blockIdx.y * 64;
    const int tid  = threadIdx.x;
    const int tm = tid >> 4;
    const int tn = tid & 15;

    float acc0[4][4] = {};
    float acc1[4][4] = {};

    for (int kk = 0; kk < H_; kk += 16) {
        {   // A tile
            const int m  = tid >> 2;
            const int k4 = (tid & 3) * 4;
            const int r  = row0 + m;
            float4 v = make_float4(0.f, 0.f, 0.f, 0.f);
            if (r < M) v = *(const float4*)(A + (size_t)r * lda + kk + k4);
            As[k4 + 0][m] = v.x; As[k4 + 1][m] = v.y;
            As[k4 + 2][m] = v.z; As[k4 + 3][m] = v.w;
        }
        {   // B0/B1 tiles
            const int k  = tid >> 4;
            const int j4 = (tid & 15) * 4;
            float4 v0 = *(const float4*)(B0 + (size_t)(kk + k) * H_ + col0 + j4);
            float4 v1 = *(const float4*)(B1 + (size_t)(kk + k) * H_ + col0 + j4);
            B0s[k][j4 + 0] = v0.x; B0s[k][j4 + 1] = v0.y;
            B0s[k][j4 + 2] = v0.z; B0s[k][j4 + 3] = v0.w;
            B1s[k][j4 + 0] = v1.x; B1s[k][j4 + 1] = v1.y;
            B1s[k][j4 + 2] = v1.z; B1s[k][j4 + 3] = v1.w;
        }
        __syncthreads();

        #pragma unroll
        for (int k = 0; k < 16; k++) {
            const float4 av  = *(const float4*)&As[k][tm * 4];
            const float4 bv0 = *(const float4*)&B0s[k][tn * 4];
            const float4 bv1 = *(const float4*)&B1s[k][tn * 4];
            const float a[4]  = {av.x, av.y, av.z, av.w};
            const float b0[4] = {bv0.x, bv0.y, bv0.z, bv0.w};
            const float b1v[4] = {bv1.x, bv1.y, bv1.z, bv1.w};
            #pragma unroll
            for (int i = 0; i < 4; i++)
                #pragma unroll
                for (int j = 0; j < 4; j++) {
                    acc0[i][j] += a[i] * b0[j];
                    acc1[i][j] += a[i] * b1v[j];
                }
        }
        __syncthreads();
    }

    #pragma unroll
    for (int i = 0; i < 4; i++) {
        const int r = row0 + tm * 4 + i;
        if (r >= M) continue;
        const float s0 = rs0[r];
        const float s1 = rs1[r];
        #pragma unroll
        for (int j = 0; j < 4; j++) {
            const int c = col0 + tn * 4 + j;
            C0[(size_t)r * H_ + c] = acc0[i][j] * s0;
            C1[(size_t)r * H_ + c] = acc1[i][j] * s1;
        }
    }
}

// ---------------------------------------------------------------------------
// Zero ints
// ---------------------------------------------------------------------------
__global__ __launch_bounds__(256) void zero_i(int* __restrict__ p, int n)
{
    int t = blockIdx.x * 256 + threadIdx.x;
    if (t < n) p[t] = 0;
}

// ---------------------------------------------------------------------------
// Degree counting: eb is the contiguous (R,2,E) int block for this sign.
// cnt layout: [which = r*2 + (0=src/out,1=dst/in)] x N
// ---------------------------------------------------------------------------
__global__ __launch_bounds__(256) void count_deg(const int* __restrict__ eb,
                                                 int* __restrict__ cnt, int total)
{
    int t = blockIdx.x * 256 + threadIdx.x;
    if (t >= total) return;
    int which = t / E_;
    atomicAdd(&cnt[which * N_ + eb[t]], 1);
}

// dscale[i] = rsqrt(max(cnt[i],1))
__global__ __launch_bounds__(256) void deg_finalize(const int* __restrict__ cnt,
                                                    float* __restrict__ dscale, int n)
{
    int t = blockIdx.x * 256 + threadIdx.x;
    if (t < n) {
        int v = cnt[t];
        dscale[t] = rsqrtf((float)(v < 1 ? 1 : v));
    }
}

// ---------------------------------------------------------------------------
// Exclusive scan of in-degree counts -> CSR offsets + cursor init.
// One block of 1024 threads per relation.
// ---------------------------------------------------------------------------
__global__ __launch_bounds__(1024) void scan_offs(const int* __restrict__ cnt,
                                                  int* __restrict__ offs,
                                                  int* __restrict__ cursor)
{
    __shared__ int part[1024];
    const int r = blockIdx.x;
    const int* in = cnt + (size_t)(2 * r + 1) * N_;
    int* out = offs + (size_t)r * (N_ + 1);
    int* cur = cursor + (size_t)r * N_;

    constexpr int CH = (N_ + 1023) / 1024;   // 49
    const int lo = threadIdx.x * CH;
    const int hi = (lo + CH < N_) ? lo + CH : N_;

    int s = 0;
    for (int i = lo; i < hi; i++) s += in[i];
    part[threadIdx.x] = s;
    __syncthreads();

    #pragma unroll
    for (int d = 1; d < 1024; d <<= 1) {
        int t = (threadIdx.x >= d) ? part[threadIdx.x - d] : 0;
        __syncthreads();
        part[threadIdx.x] += t;
        __syncthreads();
    }

    int run = part[threadIdx.x] - s;   // exclusive prefix at chunk start
    for (int i = lo; i < hi; i++) {
        int v = in[i];
        out[i] = run;
        cur[i] = run;
        run += v;
    }
    if (threadIdx.x == 1023) out[N_] = run;
}

// csr[r*E + pos] = src, bucketed by dst
__global__ __launch_bounds__(256) void csr_fill(const int* __restrict__ eb,
                                                int* __restrict__ cursor,
                                                int* __restrict__ csr, int total)
{
    int t = blockIdx.x * 256 + threadIdx.x;
    if (t >= total) return;
    int r = (t >= E_) ? 1 : 0;
    int e = t - r * E_;
    int s = eb[(r * 2 + 0) * E_ + e];
    int d = eb[(r * 2 + 1) * E_ + e];
    int pos = atomicAdd(&cursor[r * N_ + d], 1);
    csr[(size_t)r * E_ + pos] = s;
}

// ---------------------------------------------------------------------------
// Gather helper: sum m[csr[k]] rows over [b,e), unrolled x4 so 4 independent
// global_load_dwordx2 are in flight per wave (latency-bound random gather).
// ---------------------------------------------------------------------------
__device__ __forceinline__ void gather_rel(const float2* __restrict__ m,
                                           const int* __restrict__ csr,
                                           int b, int e, int lane, float2& acc)
{
    int k = b;
    for (; k + 4 <= e; k += 4) {
        const int s0 = csr[k + 0];
        const int s1 = csr[k + 1];
        const int s2 = csr[k + 2];
        const int s3 = csr[k + 3];
        const float2 v0 = m[(size_t)s0 * 64 + lane];
        const float2 v1 = m[(size_t)s1 * 64 + lane];
        const float2 v2 = m[(size_t)s2 * 64 + lane];
        const float2 v3 = m[(size_t)s3 * 64 + lane];
        acc.x += (v0.x + v1.x) + (v2.x + v3.x);
        acc.y += (v0.y + v1.y) + (v2.y + v3.y);
    }
    for (; k < e; k++) {
        const int s = csr[k];
        const float2 v = m[(size_t)s * 64 + lane];
        acc.x += v.x; acc.y += v.y;
    }
}

// ---------------------------------------------------------------------------
// Fused: CSR pull (both relations) + GCN finalize + relation attention.
// One wave per node; lane l holds columns {2l, 2l+1} as a float2.
//
// Occupancy: LDS is just W1s (32 KiB) + small vectors (~33.5 KiB total) ->
// 4 blocks/CU = 32 waves/CU (100% cap). The hsS staging buffer is gone:
// the attention matvec broadcasts each wave's own hs registers via __shfl
// (source lane is loop-uniform), so no LDS round-trip and no barrier after
// the initial weight staging. launch_bounds(512,8) caps VGPR at 64 so 8
// waves/SIMD are resident.
// ---------------------------------------------------------------------------
__global__ __launch_bounds__(512, 8) void pull_attn(
    const float2* __restrict__ m0, const float2* __restrict__ m1,
    const int* __restrict__ offs0, const int* __restrict__ csr0,
    const int* __restrict__ offs1, const int* __restrict__ csr1,
    const float* __restrict__ si0, const float* __restrict__ si1,
    const float* __restrict__ bias0, const float* __restrict__ bias1,
    const float* __restrict__ W1, const float* __restrict__ b1,
    const float* __restrict__ w2, float2* __restrict__ outb, int n)
{
    __shared__ float W1s[H_ * Q_];          // 32 KiB, layout [i*64 + q]
    __shared__ float b1s[Q_], w2s[Q_], bAs[H_], bBs[H_];

    for (int i = threadIdx.x; i < H_ * Q_; i += 512) W1s[i] = W1[i];
    if (threadIdx.x < Q_) { b1s[threadIdx.x] = b1[threadIdx.x]; w2s[threadIdx.x] = w2[threadIdx.x]; }
    {
        const int t = (int)threadIdx.x - Q_;
        if (t >= 0 && t < H_) bAs[t] = bias0[t];
        const int u = (int)threadIdx.x - Q_ - H_;
        if (u >= 0 && u < H_) bBs[u] = bias1[u];
    }
    __syncthreads();   // weights staged; the ONLY block barrier

    const int lane = threadIdx.x & 63;
    int node = (blockIdx.x * 512 + threadIdx.x) >> 6;
    node = __builtin_amdgcn_readfirstlane(node);   // wave-uniform -> scalar loads
    if (node >= n) return;                          // wave-uniform exit

    float2 a0 = make_float2(0.f, 0.f), a1 = a0;
    const int b0  = offs0[node], e0 = offs0[node + 1];
    const int b1i = offs1[node], e1 = offs1[node + 1];
    gather_rel(m0, csr0, b0,  e0, lane, a0);
    gather_rel(m1, csr1, b1i, e1, lane, a1);

    const float sc0 = si0[node], sc1 = si1[node];
    float2 hs0, hs1;
    hs0.x = a0.x * sc0 + bAs[2 * lane];
    hs0.y = a0.y * sc0 + bAs[2 * lane + 1];
    hs1.x = a1.x * sc1 + bBs[2 * lane];
    hs1.y = a1.y * sc1 + bBs[2 * lane + 1];

    // attention matvec: t[q=lane] = b1[q] + sum_i h[i] * W1[i,q]
    // h[2j], h[2j+1] live in lane j's hs registers -> broadcast via shfl.
    float t0 = b1s[lane], t1 = b1s[lane];
    #pragma unroll 8
    for (int j = 0; j < 64; j++) {
        const float h0x = __shfl(hs0.x, j);
        const float h0y = __shfl(hs0.y, j);
        const float h1x = __shfl(hs1.x, j);
        const float h1y = __shfl(hs1.y, j);
        const float wa = W1s[(2 * j) * Q_ + lane];
        const float wb = W1s[(2 * j + 1) * Q_ + lane];
        t0 += h0x * wa + h0y * wb;
        t1 += h1x * wa + h1y * wb;
    }
    float s0 = tanhf(t0) * w2s[lane];
    float s1 = tanhf(t1) * w2s[lane];
    #pragma unroll
    for (int off = 32; off > 0; off >>= 1) {
        s0 += __shfl_xor(s0, off);
        s1 += __shfl_xor(s1, off);
    }
    const float mx = fmaxf(s0, s1);
    const float e0v = expf(s0 - mx), e1v = expf(s1 - mx);
    const float aw0 = e0v / (e0v + e1v), aw1 = 1.0f - aw0;

    float2 o;
    o.x = aw0 * hs0.x + aw1 * hs1.x;
    o.y = aw0 * hs0.y + aw1 * hs1.y;
    outb[(size_t)node * 64 + lane] = o;
}

// ---------------------------------------------------------------------------
// Orchestration
// ---------------------------------------------------------------------------
extern "C" void kernel_launch(void* const* d_in, const int* in_sizes, int n_in,
                              void* d_out, int out_size, void* d_ws, size_t ws_size,
                              hipStream_t stream)
{
    const float* x_attr = (const float*)d_in[0];
    const float* x_stru = (const float*)d_in[1];
    const int*   e_attr = (const int*)d_in[2];
    const int*   e_stru = (const int*)d_in[3];
    const float* Wf     = (const float*)d_in[4];
    const float* convW  = (const float*)d_in[5];
    const float* convB  = (const float*)d_in[6];
    const float* aW1    = (const float*)d_in[7];
    const float* aB1    = (const float*)d_in[8];
    const float* aW2    = (const float*)d_in[9];
    const float* Wc     = (const float*)d_in[10];
    float*       out    = (float*)d_out;
    float*       ws     = (float*)d_ws;

    const size_t NH = (size_t)N_ * H_;
    float* A  = ws;            // h0, later h2
    float* Bb = ws + 1 * NH;   // h1, later hA
    float* C  = ws + 2 * NH;   // m0
    float* D  = ws + 3 * NH;   // m1
    float* dscale = ws + 4 * NH;                    // 4N floats [out0,in0,out1,in1]
    int*   ibase  = (int*)(dscale + 4 * N_);
    int*   cnt    = ibase;                          // 4N ints
    int*   offs   = ibase + 4 * N_;                 // 2*(N+1)
    int*   csr    = offs + 2 * (N_ + 1);            // 2*E
    int*   cursor = csr + 2 * E_;                   // 2*N

    const int GX = (N_ + 63) / 64;
    const dim3 GGRID(GX, 2);
    const int PA_B = (N_ * 64) / 512;               // pull_attn blocks (512 thr), exact

    for (int run = 0; run < 4; run++) {
        const int sign = run >> 1;
        const float* x = (run & 1) ? x_stru : x_attr;
        const int* eb = ((run & 1) ? e_stru : e_attr) + (size_t)sign * (R_ * 2 * E_);
        float* y = out + (size_t)run * NH;
        const float* WcS = Wc + (size_t)sign * H_ * 3 * H_;

        // --- degrees + CSR build (once per run, reused by all 3 layers) ---
        zero_i<<<(4 * N_ + 255) / 256, 256, 0, stream>>>(cnt, 4 * N_);
        count_deg<<<(4 * E_ + 255) / 256, 256, 0, stream>>>(eb, cnt, 4 * E_);
        deg_finalize<<<(4 * N_ + 255) / 256, 256, 0, stream>>>(cnt, dscale, 4 * N_);
        scan_offs<<<2, 1024, 0, stream>>>(cnt, offs, cursor);
        csr_fill<<<(2 * E_ + 255) / 256, 256, 0, stream>>>(eb, cursor, csr, 2 * E_);

        // --- h0 = tanh(x @ Wf^T) ---
        gemm_kernel<true><<<GGRID, 256, 0, stream>>>(
            x, F_, Wf + (size_t)sign * H_ * F_, F_, A, H_, N_, F_, nullptr, MODE_TANH);

        // --- y = h0 @ Wc[:, 0:H]^T ---
        gemm_kernel<true><<<GGRID, 256, 0, stream>>>(
            A, H_, WcS, 3 * H_, y, H_, N_, H_, nullptr, MODE_STORE);

        // --- heterogeneous layer: fused dual-relation GEMM + pull/attention ---
        auto het = [&](const float* h_in, int l, float* outb) {
            const size_t lo = (size_t)(sign * L_ + l);
            gemm_conv_pair<<<GGRID, 256, 0, stream>>>(
                h_in, H_,
                convW + (lo * R_ + 0) * H_ * H_,
                convW + (lo * R_ + 1) * H_ * H_,
                C, D, N_,
                dscale + 0 * N_, dscale + 2 * N_);
            pull_attn<<<PA_B, 512, 0, stream>>>(
                (const float2*)C, (const float2*)D,
                offs, csr, offs + (N_ + 1), csr + E_,
                dscale + N_, dscale + 3 * N_,
                convB + (lo * R_ + 0) * H_, convB + (lo * R_ + 1) * H_,
                aW1 + lo * H_ * Q_, aB1 + lo * Q_, aW2 + lo * Q_,
                (float2*)outb, N_);
        };

        // --- h1 = het(h0, layer 1); y += h1 @ Wc[:, H:2H]^T ---
        het(A, 1, Bb);
        gemm_kernel<true><<<GGRID, 256, 0, stream>>>(
            Bb, H_, WcS + H_, 3 * H_, y, H_, N_, H_, nullptr, MODE_ACC);

        // --- hA = het(h0, layer 0) (h1 consumed, reuse Bb) ---
        het(A, 0, Bb);

        // --- h2 = het(hA, layer 1) -> A (h0 dead); y += h2 @ Wc[:, 2H:3H]^T ---
        het(Bb, 1, A);
        gemm_kernel<true><<<GGRID, 256, 0, stream>>>(
            A, H_, WcS + 2 * H_, 3 * H_, y, H_, N_, H_, nullptr, MODE_ACC);
    }
}

// Round 3
// 3886.160 us; speedup vs baseline: 1.2899x; 1.2899x over previous
//
#include <hip/hip_runtime.h>
#include <math.h>

// Problem constants (fixed by the reference)
constexpr int N_ = 50000;   // nodes
constexpr int E_ = 600000;  // edges per relation
constexpr int F_ = 256;     // feature dim
constexpr int H_ = 128;     // hidden dim
constexpr int Q_ = 64;      // query dim (== one wave)
constexpr int R_ = 2;       // relations
constexpr int L_ = 2;       // conv depth

#define MODE_STORE 0
#define MODE_TANH  1
#define MODE_ACC   2

// ---------------------------------------------------------------------------
// Tiled f32 GEMM: C[M x 64*gridDim.y] = A (M x K) * B
//   BT=true : C[n,j] = sum_k A[n,k] * B[j*ldb + k]   (B^T, row-major B)
//   BT=false: C[n,j] = sum_k A[n,k] * B[k*ldb + j]
// rowscale (optional): multiply row n of the result by rowscale[n]
// Tile: 64x64, BK=16, 256 threads, 4x4 outputs/thread.
// ---------------------------------------------------------------------------
template <bool BT>
__global__ __launch_bounds__(256) void gemm_kernel(
    const float* __restrict__ A, int lda,
    const float* __restrict__ B, int ldb,
    float* __restrict__ C, int ldc,
    int M, int K,
    const float* __restrict__ rowscale, int mode)
{
    __shared__ __align__(16) float As[16][68];
    __shared__ __align__(16) float Bs[16][68];

    const int row0 = blockIdx.x * 64;
    const int col0 = blockIdx.y * 64;
    const int tid  = threadIdx.x;
    const int tm = tid >> 4;
    const int tn = tid & 15;

    float acc[4][4] = {};

    for (int kk = 0; kk < K; kk += 16) {
        {   // A tile: 64 rows x 16 k, one float4 per thread
            const int m  = tid >> 2;
            const int k4 = (tid & 3) * 4;
            const int r  = row0 + m;
            float4 v = make_float4(0.f, 0.f, 0.f, 0.f);
            if (r < M) v = *(const float4*)(A + (size_t)r * lda + kk + k4);
            As[k4 + 0][m] = v.x; As[k4 + 1][m] = v.y;
            As[k4 + 2][m] = v.z; As[k4 + 3][m] = v.w;
        }
        if (BT) {
            const int j  = tid >> 2;
            const int k4 = (tid & 3) * 4;
            float4 v = *(const float4*)(B + (size_t)(col0 + j) * ldb + kk + k4);
            Bs[k4 + 0][j] = v.x; Bs[k4 + 1][j] = v.y;
            Bs[k4 + 2][j] = v.z; Bs[k4 + 3][j] = v.w;
        } else {
            const int k  = tid >> 4;
            const int j4 = (tid & 15) * 4;
            float4 v = *(const float4*)(B + (size_t)(kk + k) * ldb + col0 + j4);
            Bs[k][j4 + 0] = v.x; Bs[k][j4 + 1] = v.y;
            Bs[k][j4 + 2] = v.z; Bs[k][j4 + 3] = v.w;
        }
        __syncthreads();

        #pragma unroll
        for (int k = 0; k < 16; k++) {
            const float4 av = *(const float4*)&As[k][tm * 4];
            const float4 bv = *(const float4*)&Bs[k][tn * 4];
            const float a[4] = {av.x, av.y, av.z, av.w};
            const float b[4] = {bv.x, bv.y, bv.z, bv.w};
            #pragma unroll
            for (int i = 0; i < 4; i++)
                #pragma unroll
                for (int j = 0; j < 4; j++)
                    acc[i][j] += a[i] * b[j];
        }
        __syncthreads();
    }

    #pragma unroll
    for (int i = 0; i < 4; i++) {
        const int r = row0 + tm * 4 + i;
        if (r >= M) continue;
        const float rs = rowscale ? rowscale[r] : 1.0f;
        #pragma unroll
        for (int j = 0; j < 4; j++) {
            const int c = col0 + tn * 4 + j;
            float v = acc[i][j] * rs;
            if (mode == MODE_TANH) v = tanhf(v);
            float* p = C + (size_t)r * ldc + c;
            if (mode == MODE_ACC) *p += v;
            else                  *p = v;
        }
    }
}

// ---------------------------------------------------------------------------
// Fused dual-relation conv GEMM (BT=false, K=H=128, ldb=ldc=128):
//   C0[n,j] = rs0[n] * sum_k A[n,k] * B0[k,j]
//   C1[n,j] = rs1[n] * sum_k A[n,k] * B1[k,j]
// One A-tile staging serves both relations.
// ---------------------------------------------------------------------------
__global__ __launch_bounds__(256) void gemm_conv_pair(
    const float* __restrict__ A, int lda,
    const float* __restrict__ B0, const float* __restrict__ B1,
    float* __restrict__ C0, float* __restrict__ C1,
    int M, const float* __restrict__ rs0, const float* __restrict__ rs1)
{
    __shared__ __align__(16) float As[16][68];
    __shared__ __align__(16) float B0s[16][68];
    __shared__ __align__(16) float B1s[16][68];

    const int row0 = blockIdx.x * 64;
    const int col0 = blockIdx.y * 64;
    const int tid  = threadIdx.x;
    const int tm = tid >> 4;
    const int tn = tid & 15;

    float acc0[4][4] = {};
    float acc1[4][4] = {};

    for (int kk = 0; kk < H_; kk += 16) {
        {   // A tile
            const int m  = tid >> 2;
            const int k4 = (tid & 3) * 4;
            const int r  = row0 + m;
            float4 v = make_float4(0.f, 0.f, 0.f, 0.f);
            if (r < M) v = *(const float4*)(A + (size_t)r * lda + kk + k4);
            As[k4 + 0][m] = v.x; As[k4 + 1][m] = v.y;
            As[k4 + 2][m] = v.z; As[k4 + 3][m] = v.w;
        }
        {   // B0/B1 tiles
            const int k  = tid >> 4;
            const int j4 = (tid & 15) * 4;
            float4 v0 = *(const float4*)(B0 + (size_t)(kk + k) * H_ + col0 + j4);
            float4 v1 = *(const float4*)(B1 + (size_t)(kk + k) * H_ + col0 + j4);
            B0s[k][j4 + 0] = v0.x; B0s[k][j4 + 1] = v0.y;
            B0s[k][j4 + 2] = v0.z; B0s[k][j4 + 3] = v0.w;
            B1s[k][j4 + 0] = v1.x; B1s[k][j4 + 1] = v1.y;
            B1s[k][j4 + 2] = v1.z; B1s[k][j4 + 3] = v1.w;
        }
        __syncthreads();

        #pragma unroll
        for (int k = 0; k < 16; k++) {
            const float4 av  = *(const float4*)&As[k][tm * 4];
            const float4 bv0 = *(const float4*)&B0s[k][tn * 4];
            const float4 bv1 = *(const float4*)&B1s[k][tn * 4];
            const float a[4]  = {av.x, av.y, av.z, av.w};
            const float b0[4] = {bv0.x, bv0.y, bv0.z, bv0.w};
            const float b1v[4] = {bv1.x, bv1.y, bv1.z, bv1.w};
            #pragma unroll
            for (int i = 0; i < 4; i++)
                #pragma unroll
                for (int j = 0; j < 4; j++) {
                    acc0[i][j] += a[i] * b0[j];
                    acc1[i][j] += a[i] * b1v[j];
                }
        }
        __syncthreads();
    }

    #pragma unroll
    for (int i = 0; i < 4; i++) {
        const int r = row0 + tm * 4 + i;
        if (r >= M) continue;
        const float s0 = rs0[r];
        const float s1 = rs1[r];
        #pragma unroll
        for (int j = 0; j < 4; j++) {
            const int c = col0 + tn * 4 + j;
            C0[(size_t)r * H_ + c] = acc0[i][j] * s0;
            C1[(size_t)r * H_ + c] = acc1[i][j] * s1;
        }
    }
}

// ---------------------------------------------------------------------------
// Zero ints
// ---------------------------------------------------------------------------
__global__ __launch_bounds__(256) void zero_i(int* __restrict__ p, int n)
{
    int t = blockIdx.x * 256 + threadIdx.x;
    if (t < n) p[t] = 0;
}

// ---------------------------------------------------------------------------
// Degree counting: eb is the contiguous (R,2,E) int block for this sign.
// cnt layout: [which = r*2 + (0=src/out,1=dst/in)] x N
// ---------------------------------------------------------------------------
__global__ __launch_bounds__(256) void count_deg(const int* __restrict__ eb,
                                                 int* __restrict__ cnt, int total)
{
    int t = blockIdx.x * 256 + threadIdx.x;
    if (t >= total) return;
    int which = t / E_;
    atomicAdd(&cnt[which * N_ + eb[t]], 1);
}

// dscale[i] = rsqrt(max(cnt[i],1))
__global__ __launch_bounds__(256) void deg_finalize(const int* __restrict__ cnt,
                                                    float* __restrict__ dscale, int n)
{
    int t = blockIdx.x * 256 + threadIdx.x;
    if (t < n) {
        int v = cnt[t];
        dscale[t] = rsqrtf((float)(v < 1 ? 1 : v));
    }
}

// ---------------------------------------------------------------------------
// Exclusive scan of in-degree counts -> CSR offsets + cursor init.
// One block of 1024 threads per relation.
// ---------------------------------------------------------------------------
__global__ __launch_bounds__(1024) void scan_offs(const int* __restrict__ cnt,
                                                  int* __restrict__ offs,
                                                  int* __restrict__ cursor)
{
    __shared__ int part[1024];
    const int r = blockIdx.x;
    const int* in = cnt + (size_t)(2 * r + 1) * N_;
    int* out = offs + (size_t)r * (N_ + 1);
    int* cur = cursor + (size_t)r * N_;

    constexpr int CH = (N_ + 1023) / 1024;   // 49
    const int lo = threadIdx.x * CH;
    const int hi = (lo + CH < N_) ? lo + CH : N_;

    int s = 0;
    for (int i = lo; i < hi; i++) s += in[i];
    part[threadIdx.x] = s;
    __syncthreads();

    #pragma unroll
    for (int d = 1; d < 1024; d <<= 1) {
        int t = (threadIdx.x >= d) ? part[threadIdx.x - d] : 0;
        __syncthreads();
        part[threadIdx.x] += t;
        __syncthreads();
    }

    int run = part[threadIdx.x] - s;   // exclusive prefix at chunk start
    for (int i = lo; i < hi; i++) {
        int v = in[i];
        out[i] = run;
        cur[i] = run;
        run += v;
    }
    if (threadIdx.x == 1023) out[N_] = run;
}

// csr[r*E + pos] = src, bucketed by dst
__global__ __launch_bounds__(256) void csr_fill(const int* __restrict__ eb,
                                                int* __restrict__ cursor,
                                                int* __restrict__ csr, int total)
{
    int t = blockIdx.x * 256 + threadIdx.x;
    if (t >= total) return;
    int r = (t >= E_) ? 1 : 0;
    int e = t - r * E_;
    int s = eb[(r * 2 + 0) * E_ + e];
    int d = eb[(r * 2 + 1) * E_ + e];
    int pos = atomicAdd(&cursor[r * N_ + d], 1);
    csr[(size_t)r * E_ + pos] = s;
}

// ---------------------------------------------------------------------------
// Gather helper: sum m[csr[k]] rows over [b,e), unrolled x4 so 4 independent
// global_load_dwordx2 are in flight per wave (latency-bound random gather).
// ---------------------------------------------------------------------------
__device__ __forceinline__ void gather_rel(const float2* __restrict__ m,
                                           const int* __restrict__ csr,
                                           int b, int e, int lane, float2& acc)
{
    int k = b;
    for (; k + 4 <= e; k += 4) {
        const int s0 = csr[k + 0];
        const int s1 = csr[k + 1];
        const int s2 = csr[k + 2];
        const int s3 = csr[k + 3];
        const float2 v0 = m[(size_t)s0 * 64 + lane];
        const float2 v1 = m[(size_t)s1 * 64 + lane];
        const float2 v2 = m[(size_t)s2 * 64 + lane];
        const float2 v3 = m[(size_t)s3 * 64 + lane];
        acc.x += (v0.x + v1.x) + (v2.x + v3.x);
        acc.y += (v0.y + v1.y) + (v2.y + v3.y);
    }
    for (; k < e; k++) {
        const int s = csr[k];
        const float2 v = m[(size_t)s * 64 + lane];
        acc.x += v.x; acc.y += v.y;
    }
}

// ---------------------------------------------------------------------------
// Fused: CSR pull (both relations) + GCN finalize + relation attention.
// One wave per node; lane l holds columns {2l, 2l+1} as a float2.
//
// This is the R1 structure (measured 122 us: hsS staging + wave-local
// lgkmcnt publish, x4 gather unroll, ~40 VGPR) with ONE change: 1024-thread
// blocks so 16 waves share the single 32 KiB W1s copy. LDS/block ~49.5 KiB
// -> 2 blocks/CU = 32 waves/CU (100% cap, vs 24 at R1). launch_bounds
// (1024,8) caps VGPR at 64 -- well above the ~40 the body uses, so the
// gather's 4-deep load pipeline is NOT squeezed (R2's 32-VGPR mistake).
// ---------------------------------------------------------------------------
__global__ __launch_bounds__(1024, 8) void pull_attn(
    const float2* __restrict__ m0, const float2* __restrict__ m1,
    const int* __restrict__ offs0, const int* __restrict__ csr0,
    const int* __restrict__ offs1, const int* __restrict__ csr1,
    const float* __restrict__ si0, const float* __restrict__ si1,
    const float* __restrict__ bias0, const float* __restrict__ bias1,
    const float* __restrict__ W1, const float* __restrict__ b1,
    const float* __restrict__ w2, float2* __restrict__ outb, int n)
{
    __shared__ float W1s[H_ * Q_];          // 32 KiB, layout [i*64 + q]
    __shared__ float2 hsS[16][2][Q_];       // per-wave hs staging, 16 KiB
    __shared__ float b1s[Q_], w2s[Q_], bAs[H_], bBs[H_];

    for (int i = threadIdx.x; i < H_ * Q_; i += 1024) W1s[i] = W1[i];
    if (threadIdx.x < Q_) { b1s[threadIdx.x] = b1[threadIdx.x]; w2s[threadIdx.x] = w2[threadIdx.x]; }
    {
        const int t = (int)threadIdx.x - Q_;
        if (t >= 0 && t < H_) bAs[t] = bias0[t];
        const int u = (int)threadIdx.x - Q_ - H_;
        if (u >= 0 && u < H_) bBs[u] = bias1[u];
    }
    __syncthreads();   // weights staged; the ONLY block barrier

    const int lane = threadIdx.x & 63;
    const int wv   = threadIdx.x >> 6;
    int node = (blockIdx.x * 1024 + threadIdx.x) >> 6;
    node = __builtin_amdgcn_readfirstlane(node);   // wave-uniform -> scalar loads

    float2 hs0 = make_float2(0.f, 0.f), hs1 = hs0;

    if (node < n) {
        float2 a0 = make_float2(0.f, 0.f), a1 = a0;
        const int b0  = offs0[node], e0 = offs0[node + 1];
        const int b1i = offs1[node], e1 = offs1[node + 1];
        gather_rel(m0, csr0, b0,  e0, lane, a0);
        gather_rel(m1, csr1, b1i, e1, lane, a1);

        const float sc0 = si0[node], sc1 = si1[node];
        hs0.x = a0.x * sc0 + bAs[2 * lane];
        hs0.y = a0.y * sc0 + bAs[2 * lane + 1];
        hs1.x = a1.x * sc1 + bBs[2 * lane];
        hs1.y = a1.y * sc1 + bBs[2 * lane + 1];
        hsS[wv][0][lane] = hs0;
        hsS[wv][1][lane] = hs1;
    }

    // Wave-local publish of hsS: lanes are lockstep within a wave; draining
    // lgkmcnt makes every lane's ds_write visible to every lane's ds_read.
    __asm__ volatile("s_waitcnt lgkmcnt(0)" ::: "memory");
    __builtin_amdgcn_sched_barrier(0);

    if (node < n) {
        const float* h0p = (const float*)&hsS[wv][0][0];
        const float* h1p = (const float*)&hsS[wv][1][0];
        float t0 = b1s[lane], t1 = b1s[lane];
        #pragma unroll 8
        for (int i = 0; i < H_; i++) {
            const float wval = W1s[i * Q_ + lane];
            t0 += h0p[i] * wval;
            t1 += h1p[i] * wval;
        }
        float s0 = tanhf(t0) * w2s[lane];
        float s1 = tanhf(t1) * w2s[lane];
        #pragma unroll
        for (int off = 32; off > 0; off >>= 1) {
            s0 += __shfl_xor(s0, off);
            s1 += __shfl_xor(s1, off);
        }
        const float mx = fmaxf(s0, s1);
        const float e0v = expf(s0 - mx), e1v = expf(s1 - mx);
        const float a0 = e0v / (e0v + e1v), a1 = 1.0f - a0;

        float2 o;
        o.x = a0 * hs0.x + a1 * hs1.x;
        o.y = a0 * hs0.y + a1 * hs1.y;
        outb[(size_t)node * 64 + lane] = o;
    }
}

// ---------------------------------------------------------------------------
// Orchestration
// ---------------------------------------------------------------------------
extern "C" void kernel_launch(void* const* d_in, const int* in_sizes, int n_in,
                              void* d_out, int out_size, void* d_ws, size_t ws_size,
                              hipStream_t stream)
{
    const float* x_attr = (const float*)d_in[0];
    const float* x_stru = (const float*)d_in[1];
    const int*   e_attr = (const int*)d_in[2];
    const int*   e_stru = (const int*)d_in[3];
    const float* Wf     = (const float*)d_in[4];
    const float* convW  = (const float*)d_in[5];
    const float* convB  = (const float*)d_in[6];
    const float* aW1    = (const float*)d_in[7];
    const float* aB1    = (const float*)d_in[8];
    const float* aW2    = (const float*)d_in[9];
    const float* Wc     = (const float*)d_in[10];
    float*       out    = (float*)d_out;
    float*       ws     = (float*)d_ws;

    const size_t NH = (size_t)N_ * H_;
    float* A  = ws;            // h0, later h2
    float* Bb = ws + 1 * NH;   // h1, later hA
    float* C  = ws + 2 * NH;   // m0
    float* D  = ws + 3 * NH;   // m1
    float* dscale = ws + 4 * NH;                    // 4N floats [out0,in0,out1,in1]
    int*   ibase  = (int*)(dscale + 4 * N_);
    int*   cnt    = ibase;                          // 4N ints
    int*   offs   = ibase + 4 * N_;                 // 2*(N+1)
    int*   csr    = offs + 2 * (N_ + 1);            // 2*E
    int*   cursor = csr + 2 * E_;                   // 2*N

    const int GX = (N_ + 63) / 64;
    const dim3 GGRID(GX, 2);
    const int PA_B = (N_ * 64) / 1024;              // pull_attn blocks (1024 thr), exact

    for (int run = 0; run < 4; run++) {
        const int sign = run >> 1;
        const float* x = (run & 1) ? x_stru : x_attr;
        const int* eb = ((run & 1) ? e_stru : e_attr) + (size_t)sign * (R_ * 2 * E_);
        float* y = out + (size_t)run * NH;
        const float* WcS = Wc + (size_t)sign * H_ * 3 * H_;

        // --- degrees + CSR build (once per run, reused by all 3 layers) ---
        zero_i<<<(4 * N_ + 255) / 256, 256, 0, stream>>>(cnt, 4 * N_);
        count_deg<<<(4 * E_ + 255) / 256, 256, 0, stream>>>(eb, cnt, 4 * E_);
        deg_finalize<<<(4 * N_ + 255) / 256, 256, 0, stream>>>(cnt, dscale, 4 * N_);
        scan_offs<<<2, 1024, 0, stream>>>(cnt, offs, cursor);
        csr_fill<<<(2 * E_ + 255) / 256, 256, 0, stream>>>(eb, cursor, csr, 2 * E_);

        // --- h0 = tanh(x @ Wf^T) ---
        gemm_kernel<true><<<GGRID, 256, 0, stream>>>(
            x, F_, Wf + (size_t)sign * H_ * F_, F_, A, H_, N_, F_, nullptr, MODE_TANH);

        // --- y = h0 @ Wc[:, 0:H]^T ---
        gemm_kernel<true><<<GGRID, 256, 0, stream>>>(
            A, H_, WcS, 3 * H_, y, H_, N_, H_, nullptr, MODE_STORE);

        // --- heterogeneous layer: fused dual-relation GEMM + pull/attention ---
        auto het = [&](const float* h_in, int l, float* outb) {
            const size_t lo = (size_t)(sign * L_ + l);
            gemm_conv_pair<<<GGRID, 256, 0, stream>>>(
                h_in, H_,
                convW + (lo * R_ + 0) * H_ * H_,
                convW + (lo * R_ + 1) * H_ * H_,
                C, D, N_,
                dscale + 0 * N_, dscale + 2 * N_);
            pull_attn<<<PA_B, 1024, 0, stream>>>(
                (const float2*)C, (const float2*)D,
                offs, csr, offs + (N_ + 1), csr + E_,
                dscale + N_, dscale + 3 * N_,
                convB + (lo * R_ + 0) * H_, convB + (lo * R_ + 1) * H_,
                aW1 + lo * H_ * Q_, aB1 + lo * Q_, aW2 + lo * Q_,
                (float2*)outb, N_);
        };

        // --- h1 = het(h0, layer 1); y += h1 @ Wc[:, H:2H]^T ---
        het(A, 1, Bb);
        gemm_kernel<true><<<GGRID, 256, 0, stream>>>(
            Bb, H_, WcS + H_, 3 * H_, y, H_, N_, H_, nullptr, MODE_ACC);

        // --- hA = het(h0, layer 0) (h1 consumed, reuse Bb) ---
        het(A, 0, Bb);

        // --- h2 = het(hA, layer 1) -> A (h0 dead); y += h2 @ Wc[:, 2H:3H]^T ---
        het(Bb, 1, A);
        gemm_kernel<true><<<GGRID, 256, 0, stream>>>(
            A, H_, WcS + 2 * H_, 3 * H_, y, H_, N_, H_, nullptr, MODE_ACC);
    }
}

// Round 4
// 3659.925 us; speedup vs baseline: 1.3696x; 1.0618x over previous
//
#include <hip/hip_runtime.h>
#include <math.h>

// Problem constants (fixed by the reference)
constexpr int N_ = 50000;   // nodes
constexpr int E_ = 600000;  // edges per relation
constexpr int F_ = 256;     // feature dim
constexpr int H_ = 128;     // hidden dim
constexpr int Q_ = 64;      // query dim (== one wave)
constexpr int R_ = 2;       // relations
constexpr int L_ = 2;       // conv depth

#define MODE_STORE 0
#define MODE_TANH  1
#define MODE_ACC   2

// ---------------------------------------------------------------------------
// Tiled f32 GEMM, 64 rows x 128 cols per block (all our outputs are 128 wide).
//   BT=true : C[n,j] = sum_k A[n,k] * B[j*ldb + k]   (B^T, row-major B)
//   BT=false: C[n,j] = sum_k A[n,k] * B[k*ldb + j]
// 256 threads, BK=16, 4x8 outputs/thread: 32 FMA per 3 LDS float4 reads
// (vs 16:2 at 64x64) -> VALU-dominant inner loop.
// ---------------------------------------------------------------------------
template <bool BT>
__global__ __launch_bounds__(256) void gemm_kernel(
    const float* __restrict__ A, int lda,
    const float* __restrict__ B, int ldb,
    float* __restrict__ C, int ldc,
    int M, int K,
    const float* __restrict__ rowscale, int mode)
{
    __shared__ __align__(16) float As[16][68];
    __shared__ __align__(16) float Bs[16][132];

    const int row0 = blockIdx.x * 64;
    const int col0 = blockIdx.y * 128;
    const int tid  = threadIdx.x;
    const int tm = tid >> 4;    // 0..15, 4 rows each
    const int tn = tid & 15;    // 0..15, 8 cols each

    float acc[4][8] = {};

    for (int kk = 0; kk < K; kk += 16) {
        {   // A tile: 64 rows x 16 k, one float4 per thread
            const int m  = tid >> 2;
            const int k4 = (tid & 3) * 4;
            const int r  = row0 + m;
            float4 v = make_float4(0.f, 0.f, 0.f, 0.f);
            if (r < M) v = *(const float4*)(A + (size_t)r * lda + kk + k4);
            As[k4 + 0][m] = v.x; As[k4 + 1][m] = v.y;
            As[k4 + 2][m] = v.z; As[k4 + 3][m] = v.w;
        }
        if (BT) {
            // B rows are output cols: 128 j x 16 k, 8 floats (2 float4) / thread
            const int j  = tid >> 1;          // 0..127
            const int k8 = (tid & 1) * 8;     // 0 or 8
            const float* bp = B + (size_t)(col0 + j) * ldb + kk + k8;
            float4 v0 = *(const float4*)(bp);
            float4 v1 = *(const float4*)(bp + 4);
            Bs[k8 + 0][j] = v0.x; Bs[k8 + 1][j] = v0.y;
            Bs[k8 + 2][j] = v0.z; Bs[k8 + 3][j] = v0.w;
            Bs[k8 + 4][j] = v1.x; Bs[k8 + 5][j] = v1.y;
            Bs[k8 + 6][j] = v1.z; Bs[k8 + 7][j] = v1.w;
        } else {
            // 16 k x 128 cols, 2 float4 / thread
            const int k  = tid >> 5;          // 0..7
            const int j4 = (tid & 31) * 4;    // 0..124
            float4 v0 = *(const float4*)(B + (size_t)(kk + k) * ldb + col0 + j4);
            float4 v1 = *(const float4*)(B + (size_t)(kk + k + 8) * ldb + col0 + j4);
            Bs[k + 0][j4 + 0] = v0.x; Bs[k + 0][j4 + 1] = v0.y;
            Bs[k + 0][j4 + 2] = v0.z; Bs[k + 0][j4 + 3] = v0.w;
            Bs[k + 8][j4 + 0] = v1.x; Bs[k + 8][j4 + 1] = v1.y;
            Bs[k + 8][j4 + 2] = v1.z; Bs[k + 8][j4 + 3] = v1.w;
        }
        __syncthreads();

        #pragma unroll
        for (int k = 0; k < 16; k++) {
            const float4 av  = *(const float4*)&As[k][tm * 4];
            const float4 bv0 = *(const float4*)&Bs[k][tn * 8];
            const float4 bv1 = *(const float4*)&Bs[k][tn * 8 + 4];
            const float a[4] = {av.x, av.y, av.z, av.w};
            const float b[8] = {bv0.x, bv0.y, bv0.z, bv0.w,
                                bv1.x, bv1.y, bv1.z, bv1.w};
            #pragma unroll
            for (int i = 0; i < 4; i++)
                #pragma unroll
                for (int j = 0; j < 8; j++)
                    acc[i][j] += a[i] * b[j];
        }
        __syncthreads();
    }

    #pragma unroll
    for (int i = 0; i < 4; i++) {
        const int r = row0 + tm * 4 + i;
        if (r >= M) continue;
        const float rs = rowscale ? rowscale[r] : 1.0f;
        #pragma unroll
        for (int j = 0; j < 8; j++) {
            const int c = col0 + tn * 8 + j;
            float v = acc[i][j] * rs;
            if (mode == MODE_TANH) v = tanhf(v);
            float* p = C + (size_t)r * ldc + c;
            if (mode == MODE_ACC) *p += v;
            else                  *p = v;
        }
    }
}

// ---------------------------------------------------------------------------
// Fused dual-relation conv GEMM (BT=false, K=H=128, ldb=ldc=128):
//   C0[n,j] = rs0[n] * sum_k A[n,k] * B0[k,j]
//   C1[n,j] = rs1[n] * sum_k A[n,k] * B1[k,j]
// One A-tile staging serves both relations. 64x64 tiles, gridDim.y=2.
// ---------------------------------------------------------------------------
__global__ __launch_bounds__(256) void gemm_conv_pair(
    const float* __restrict__ A, int lda,
    const float* __restrict__ B0, const float* __restrict__ B1,
    float* __restrict__ C0, float* __restrict__ C1,
    int M, const float* __restrict__ rs0, const float* __restrict__ rs1)
{
    __shared__ __align__(16) float As[16][68];
    __shared__ __align__(16) float B0s[16][68];
    __shared__ __align__(16) float B1s[16][68];

    const int row0 = blockIdx.x * 64;
    const int col0 = blockIdx.y * 64;
    const int tid  = threadIdx.x;
    const int tm = tid >> 4;
    const int tn = tid & 15;

    float acc0[4][4] = {};
    float acc1[4][4] = {};

    for (int kk = 0; kk < H_; kk += 16) {
        {   // A tile
            const int m  = tid >> 2;
            const int k4 = (tid & 3) * 4;
            const int r  = row0 + m;
            float4 v = make_float4(0.f, 0.f, 0.f, 0.f);
            if (r < M) v = *(const float4*)(A + (size_t)r * lda + kk + k4);
            As[k4 + 0][m] = v.x; As[k4 + 1][m] = v.y;
            As[k4 + 2][m] = v.z; As[k4 + 3][m] = v.w;
        }
        {   // B0/B1 tiles
            const int k  = tid >> 4;
            const int j4 = (tid & 15) * 4;
            float4 v0 = *(const float4*)(B0 + (size_t)(kk + k) * H_ + col0 + j4);
            float4 v1 = *(const float4*)(B1 + (size_t)(kk + k) * H_ + col0 + j4);
            B0s[k][j4 + 0] = v0.x; B0s[k][j4 + 1] = v0.y;
            B0s[k][j4 + 2] = v0.z; B0s[k][j4 + 3] = v0.w;
            B1s[k][j4 + 0] = v1.x; B1s[k][j4 + 1] = v1.y;
            B1s[k][j4 + 2] = v1.z; B1s[k][j4 + 3] = v1.w;
        }
        __syncthreads();

        #pragma unroll
        for (int k = 0; k < 16; k++) {
            const float4 av  = *(const float4*)&As[k][tm * 4];
            const float4 bv0 = *(const float4*)&B0s[k][tn * 4];
            const float4 bv1 = *(const float4*)&B1s[k][tn * 4];
            const float a[4]  = {av.x, av.y, av.z, av.w};
            const float b0[4] = {bv0.x, bv0.y, bv0.z, bv0.w};
            const float b1v[4] = {bv1.x, bv1.y, bv1.z, bv1.w};
            #pragma unroll
            for (int i = 0; i < 4; i++)
                #pragma unroll
                for (int j = 0; j < 4; j++) {
                    acc0[i][j] += a[i] * b0[j];
                    acc1[i][j] += a[i] * b1v[j];
                }
        }
        __syncthreads();
    }

    #pragma unroll
    for (int i = 0; i < 4; i++) {
        const int r = row0 + tm * 4 + i;
        if (r >= M) continue;
        const float s0 = rs0[r];
        const float s1 = rs1[r];
        #pragma unroll
        for (int j = 0; j < 4; j++) {
            const int c = col0 + tn * 4 + j;
            C0[(size_t)r * H_ + c] = acc0[i][j] * s0;
            C1[(size_t)r * H_ + c] = acc1[i][j] * s1;
        }
    }
}

// ---------------------------------------------------------------------------
// Zero ints
// ---------------------------------------------------------------------------
__global__ __launch_bounds__(256) void zero_i(int* __restrict__ p, int n)
{
    int t = blockIdx.x * 256 + threadIdx.x;
    if (t < n) p[t] = 0;
}

// ---------------------------------------------------------------------------
// Degree counting: eb is the contiguous (R,2,E) int block for this sign.
// cnt layout: [which = r*2 + (0=src/out,1=dst/in)] x N
// ---------------------------------------------------------------------------
__global__ __launch_bounds__(256) void count_deg(const int* __restrict__ eb,
                                                 int* __restrict__ cnt, int total)
{
    int t = blockIdx.x * 256 + threadIdx.x;
    if (t >= total) return;
    int which = t / E_;
    atomicAdd(&cnt[which * N_ + eb[t]], 1);
}

// dscale[i] = rsqrt(max(cnt[i],1))
__global__ __launch_bounds__(256) void deg_finalize(const int* __restrict__ cnt,
                                                    float* __restrict__ dscale, int n)
{
    int t = blockIdx.x * 256 + threadIdx.x;
    if (t < n) {
        int v = cnt[t];
        dscale[t] = rsqrtf((float)(v < 1 ? 1 : v));
    }
}

// ---------------------------------------------------------------------------
// 3-phase parallel exclusive scan of in-degree counts -> CSR offsets+cursor.
// Replaces the 2-block scan_offs (113 us at 0.1% HBM / 0.02% VALU: 2 CUs
// busy on a 256-CU chip, stride-49 uncoalesced serial reads). All phases
// are coalesced and device-wide. Total per relation == E_ exactly, so the
// final offs[N] needs no reduction.
// ---------------------------------------------------------------------------
constexpr int SCAN_NB = (N_ + 255) / 256;   // 196 blocks per relation

// phase 1: per-256-element block sums. grid (SCAN_NB, 2)
__global__ __launch_bounds__(256) void scan_p1(const int* __restrict__ cnt,
                                               int* __restrict__ bsums)
{
    const int r = blockIdx.y;
    const int* in = cnt + (size_t)(2 * r + 1) * N_;
    const int i = blockIdx.x * 256 + threadIdx.x;
    int v = (i < N_) ? in[i] : 0;
    #pragma unroll
    for (int off = 32; off > 0; off >>= 1) v += __shfl_xor(v, off);
    __shared__ int ws[4];
    if ((threadIdx.x & 63) == 0) ws[threadIdx.x >> 6] = v;
    __syncthreads();
    if (threadIdx.x == 0)
        bsums[r * SCAN_NB + blockIdx.x] = ws[0] + ws[1] + ws[2] + ws[3];
}

// phase 2: exclusive scan of the SCAN_NB block sums. grid (2)
__global__ __launch_bounds__(256) void scan_p2(int* __restrict__ bsums)
{
    __shared__ int sh[256];
    const int r = blockIdx.x;
    const int t = threadIdx.x;
    int v = (t < SCAN_NB) ? bsums[r * SCAN_NB + t] : 0;
    sh[t] = v;
    __syncthreads();
    #pragma unroll
    for (int d = 1; d < 256; d <<= 1) {
        int u = (t >= d) ? sh[t - d] : 0;
        __syncthreads();
        sh[t] += u;
        __syncthreads();
    }
    if (t < SCAN_NB) bsums[r * SCAN_NB + t] = sh[t] - v;   // exclusive
}

// phase 3: block-local exclusive scan + block prefix -> offs, cursor.
__global__ __launch_bounds__(256) void scan_p3(const int* __restrict__ cnt,
                                               const int* __restrict__ bsums,
                                               int* __restrict__ offs,
                                               int* __restrict__ cursor)
{
    __shared__ int sh[256];
    const int r = blockIdx.y;
    const int* in = cnt + (size_t)(2 * r + 1) * N_;
    int* out = offs + (size_t)r * (N_ + 1);
    int* cur = cursor + (size_t)r * N_;
    const int i = blockIdx.x * 256 + threadIdx.x;
    const int t = threadIdx.x;
    int v = (i < N_) ? in[i] : 0;
    sh[t] = v;
    __syncthreads();
    #pragma unroll
    for (int d = 1; d < 256; d <<= 1) {
        int u = (t >= d) ? sh[t - d] : 0;
        __syncthreads();
        sh[t] += u;
        __syncthreads();
    }
    const int excl = sh[t] - v + bsums[r * SCAN_NB + blockIdx.x];
    if (i < N_) { out[i] = excl; cur[i] = excl; }
    if (i == 0) out[N_] = E_;   // every edge has a dst -> total == E_
}

// csr[r*E + pos] = src, bucketed by dst
__global__ __launch_bounds__(256) void csr_fill(const int* __restrict__ eb,
                                                int* __restrict__ cursor,
                                                int* __restrict__ csr, int total)
{
    int t = blockIdx.x * 256 + threadIdx.x;
    if (t >= total) return;
    int r = (t >= E_) ? 1 : 0;
    int e = t - r * E_;
    int s = eb[(r * 2 + 0) * E_ + e];
    int d = eb[(r * 2 + 1) * E_ + e];
    int pos = atomicAdd(&cursor[r * N_ + d], 1);
    csr[(size_t)r * E_ + pos] = s;
}

// ---------------------------------------------------------------------------
// Gather helper: sum m[csr[k]] rows over [b,e), unrolled x8 so up to 8
// independent global_load_dwordx2 are in flight per wave (latency-bound
// random gather; avg degree 12 so most nodes take one 8-batch + tail).
// ---------------------------------------------------------------------------
__device__ __forceinline__ void gather_rel(const float2* __restrict__ m,
                                           const int* __restrict__ csr,
                                           int b, int e, int lane, float2& acc)
{
    int k = b;
    for (; k + 8 <= e; k += 8) {
        int s[8];
        #pragma unroll
        for (int u = 0; u < 8; u++) s[u] = csr[k + u];
        float2 v[8];
        #pragma unroll
        for (int u = 0; u < 8; u++) v[u] = m[(size_t)s[u] * 64 + lane];
        #pragma unroll
        for (int u = 0; u < 8; u++) { acc.x += v[u].x; acc.y += v[u].y; }
    }
    if (k + 4 <= e) {
        const int s0 = csr[k + 0];
        const int s1 = csr[k + 1];
        const int s2 = csr[k + 2];
        const int s3 = csr[k + 3];
        const float2 v0 = m[(size_t)s0 * 64 + lane];
        const float2 v1 = m[(size_t)s1 * 64 + lane];
        const float2 v2 = m[(size_t)s2 * 64 + lane];
        const float2 v3 = m[(size_t)s3 * 64 + lane];
        acc.x += (v0.x + v1.x) + (v2.x + v3.x);
        acc.y += (v0.y + v1.y) + (v2.y + v3.y);
        k += 4;
    }
    for (; k < e; k++) {
        const int s = csr[k];
        const float2 v = m[(size_t)s * 64 + lane];
        acc.x += v.x; acc.y += v.y;
    }
}

// ---------------------------------------------------------------------------
// Fused: CSR pull (both relations) + GCN finalize + relation attention.
// One wave per node; lane l holds columns {2l, 2l+1} as a float2.
// 1024-thread blocks: 16 waves share one 32 KiB W1s copy; 2 blocks/CU =
// 32 waves/CU. launch_bounds(1024,8) caps VGPR at 64 (R3 measured 24, so
// the deeper x8 gather pipeline has headroom).
// ---------------------------------------------------------------------------
__global__ __launch_bounds__(1024, 8) void pull_attn(
    const float2* __restrict__ m0, const float2* __restrict__ m1,
    const int* __restrict__ offs0, const int* __restrict__ csr0,
    const int* __restrict__ offs1, const int* __restrict__ csr1,
    const float* __restrict__ si0, const float* __restrict__ si1,
    const float* __restrict__ bias0, const float* __restrict__ bias1,
    const float* __restrict__ W1, const float* __restrict__ b1,
    const float* __restrict__ w2, float2* __restrict__ outb, int n)
{
    __shared__ float W1s[H_ * Q_];          // 32 KiB, layout [i*64 + q]
    __shared__ float2 hsS[16][2][Q_];       // per-wave hs staging, 16 KiB
    __shared__ float b1s[Q_], w2s[Q_], bAs[H_], bBs[H_];

    for (int i = threadIdx.x; i < H_ * Q_; i += 1024) W1s[i] = W1[i];
    if (threadIdx.x < Q_) { b1s[threadIdx.x] = b1[threadIdx.x]; w2s[threadIdx.x] = w2[threadIdx.x]; }
    {
        const int t = (int)threadIdx.x - Q_;
        if (t >= 0 && t < H_) bAs[t] = bias0[t];
        const int u = (int)threadIdx.x - Q_ - H_;
        if (u >= 0 && u < H_) bBs[u] = bias1[u];
    }
    __syncthreads();   // weights staged; the ONLY block barrier

    const int lane = threadIdx.x & 63;
    const int wv   = threadIdx.x >> 6;
    int node = (blockIdx.x * 1024 + threadIdx.x) >> 6;
    node = __builtin_amdgcn_readfirstlane(node);   // wave-uniform -> scalar loads

    float2 hs0 = make_float2(0.f, 0.f), hs1 = hs0;

    if (node < n) {
        float2 a0 = make_float2(0.f, 0.f), a1 = a0;
        const int b0  = offs0[node], e0 = offs0[node + 1];
        const int b1i = offs1[node], e1 = offs1[node + 1];
        gather_rel(m0, csr0, b0,  e0, lane, a0);
        gather_rel(m1, csr1, b1i, e1, lane, a1);

        const float sc0 = si0[node], sc1 = si1[node];
        hs0.x = a0.x * sc0 + bAs[2 * lane];
        hs0.y = a0.y * sc0 + bAs[2 * lane + 1];
        hs1.x = a1.x * sc1 + bBs[2 * lane];
        hs1.y = a1.y * sc1 + bBs[2 * lane + 1];
        hsS[wv][0][lane] = hs0;
        hsS[wv][1][lane] = hs1;
    }

    // Wave-local publish of hsS: lanes are lockstep within a wave; draining
    // lgkmcnt makes every lane's ds_write visible to every lane's ds_read.
    __asm__ volatile("s_waitcnt lgkmcnt(0)" ::: "memory");
    __builtin_amdgcn_sched_barrier(0);

    if (node < n) {
        const float* h0p = (const float*)&hsS[wv][0][0];
        const float* h1p = (const float*)&hsS[wv][1][0];
        float t0 = b1s[lane], t1 = b1s[lane];
        #pragma unroll 8
        for (int i = 0; i < H_; i++) {
            const float wval = W1s[i * Q_ + lane];
            t0 += h0p[i] * wval;
            t1 += h1p[i] * wval;
        }
        float s0 = tanhf(t0) * w2s[lane];
        float s1 = tanhf(t1) * w2s[lane];
        #pragma unroll
        for (int off = 32; off > 0; off >>= 1) {
            s0 += __shfl_xor(s0, off);
            s1 += __shfl_xor(s1, off);
        }
        const float mx = fmaxf(s0, s1);
        const float e0v = expf(s0 - mx), e1v = expf(s1 - mx);
        const float a0 = e0v / (e0v + e1v), a1 = 1.0f - a0;

        float2 o;
        o.x = a0 * hs0.x + a1 * hs1.x;
        o.y = a0 * hs0.y + a1 * hs1.y;
        outb[(size_t)node * 64 + lane] = o;
    }
}

// ---------------------------------------------------------------------------
// Orchestration
// ---------------------------------------------------------------------------
extern "C" void kernel_launch(void* const* d_in, const int* in_sizes, int n_in,
                              void* d_out, int out_size, void* d_ws, size_t ws_size,
                              hipStream_t stream)
{
    const float* x_attr = (const float*)d_in[0];
    const float* x_stru = (const float*)d_in[1];
    const int*   e_attr = (const int*)d_in[2];
    const int*   e_stru = (const int*)d_in[3];
    const float* Wf     = (const float*)d_in[4];
    const float* convW  = (const float*)d_in[5];
    const float* convB  = (const float*)d_in[6];
    const float* aW1    = (const float*)d_in[7];
    const float* aB1    = (const float*)d_in[8];
    const float* aW2    = (const float*)d_in[9];
    const float* Wc     = (const float*)d_in[10];
    float*       out    = (float*)d_out;
    float*       ws     = (float*)d_ws;

    const size_t NH = (size_t)N_ * H_;
    float* A  = ws;            // h0, later h2
    float* Bb = ws + 1 * NH;   // h1, later hA
    float* C  = ws + 2 * NH;   // m0
    float* D  = ws + 3 * NH;   // m1
    float* dscale = ws + 4 * NH;                    // 4N floats [out0,in0,out1,in1]
    int*   ibase  = (int*)(dscale + 4 * N_);
    int*   cnt    = ibase;                          // 4N ints
    int*   offs   = ibase + 4 * N_;                 // 2*(N+1)
    int*   csr    = offs + 2 * (N_ + 1);            // 2*E
    int*   cursor = csr + 2 * E_;                   // 2*N
    int*   bsums  = cursor + 2 * N_;                // 2*SCAN_NB

    const int GX = (N_ + 63) / 64;
    const dim3 GGEMM(GX, 1);                        // 64x128 tiles, full width
    const dim3 GCONV(GX, 2);                        // conv_pair: 64x64 tiles
    const dim3 GSCAN(SCAN_NB, 2);
    const int PA_B = (N_ * 64) / 1024;              // pull_attn blocks, exact

    for (int run = 0; run < 4; run++) {
        const int sign = run >> 1;
        const float* x = (run & 1) ? x_stru : x_attr;
        const int* eb = ((run & 1) ? e_stru : e_attr) + (size_t)sign * (R_ * 2 * E_);
        float* y = out + (size_t)run * NH;
        const float* WcS = Wc + (size_t)sign * H_ * 3 * H_;

        // --- degrees + CSR build (once per run, reused by all 3 layers) ---
        zero_i<<<(4 * N_ + 255) / 256, 256, 0, stream>>>(cnt, 4 * N_);
        count_deg<<<(4 * E_ + 255) / 256, 256, 0, stream>>>(eb, cnt, 4 * E_);
        deg_finalize<<<(4 * N_ + 255) / 256, 256, 0, stream>>>(cnt, dscale, 4 * N_);
        scan_p1<<<GSCAN, 256, 0, stream>>>(cnt, bsums);
        scan_p2<<<2, 256, 0, stream>>>(bsums);
        scan_p3<<<GSCAN, 256, 0, stream>>>(cnt, bsums, offs, cursor);
        csr_fill<<<(2 * E_ + 255) / 256, 256, 0, stream>>>(eb, cursor, csr, 2 * E_);

        // --- h0 = tanh(x @ Wf^T) ---
        gemm_kernel<true><<<GGEMM, 256, 0, stream>>>(
            x, F_, Wf + (size_t)sign * H_ * F_, F_, A, H_, N_, F_, nullptr, MODE_TANH);

        // --- y = h0 @ Wc[:, 0:H]^T ---
        gemm_kernel<true><<<GGEMM, 256, 0, stream>>>(
            A, H_, WcS, 3 * H_, y, H_, N_, H_, nullptr, MODE_STORE);

        // --- heterogeneous layer: fused dual-relation GEMM + pull/attention ---
        auto het = [&](const float* h_in, int l, float* outb) {
            const size_t lo = (size_t)(sign * L_ + l);
            gemm_conv_pair<<<GCONV, 256, 0, stream>>>(
                h_in, H_,
                convW + (lo * R_ + 0) * H_ * H_,
                convW + (lo * R_ + 1) * H_ * H_,
                C, D, N_,
                dscale + 0 * N_, dscale + 2 * N_);
            pull_attn<<<PA_B, 1024, 0, stream>>>(
                (const float2*)C, (const float2*)D,
                offs, csr, offs + (N_ + 1), csr + E_,
                dscale + N_, dscale + 3 * N_,
                convB + (lo * R_ + 0) * H_, convB + (lo * R_ + 1) * H_,
                aW1 + lo * H_ * Q_, aB1 + lo * Q_, aW2 + lo * Q_,
                (float2*)outb, N_);
        };

        // --- h1 = het(h0, layer 1); y += h1 @ Wc[:, H:2H]^T ---
        het(A, 1, Bb);
        gemm_kernel<true><<<GGEMM, 256, 0, stream>>>(
            Bb, H_, WcS + H_, 3 * H_, y, H_, N_, H_, nullptr, MODE_ACC);

        // --- hA = het(h0, layer 0) (h1 consumed, reuse Bb) ---
        het(A, 0, Bb);

        // --- h2 = het(hA, layer 1) -> A (h0 dead); y += h2 @ Wc[:, 2H:3H]^T ---
        het(Bb, 1, A);
        gemm_kernel<true><<<GGEMM, 256, 0, stream>>>(
            A, H_, WcS + 2 * H_, 3 * H_, y, H_, N_, H_, nullptr, MODE_ACC);
    }
}

// Round 5
// 3466.710 us; speedup vs baseline: 1.4459x; 1.0557x over previous
//
#include <hip/hip_runtime.h>
#include <math.h>

// Problem constants (fixed by the reference)
constexpr int N_ = 50000;   // nodes
constexpr int E_ = 600000;  // edges per relation
constexpr int F_ = 256;     // feature dim
constexpr int H_ = 128;     // hidden dim
constexpr int Q_ = 64;      // query dim (== one wave)
constexpr int R_ = 2;       // relations
constexpr int L_ = 2;       // conv depth

#define MODE_STORE 0
#define MODE_TANH  1
#define MODE_ACC   2

// ---------------------------------------------------------------------------
// Tiled f32 GEMM, 64 rows x 128 cols per block, register-prefetch +
// LDS double-buffer: global loads for tile k+1 are issued BEFORE computing
// tile k (latency hidden under 512 FMA/thread), single barrier per K-step.
//   BT=true : C[n,j] = sum_k A[n,k] * B[j*ldb + k]   (B^T, row-major B)
//   BT=false: C[n,j] = sum_k A[n,k] * B[k*ldb + j]
// ---------------------------------------------------------------------------
template <bool BT>
__global__ __launch_bounds__(256) void gemm_kernel(
    const float* __restrict__ A, int lda,
    const float* __restrict__ B, int ldb,
    float* __restrict__ C, int ldc,
    int M, int K,
    const float* __restrict__ rowscale, int mode)
{
    __shared__ __align__(16) float As[2][16][68];
    __shared__ __align__(16) float Bs[2][16][132];

    const int row0 = blockIdx.x * 64;
    const int col0 = blockIdx.y * 128;
    const int tid  = threadIdx.x;
    const int tm = tid >> 4;    // 0..15, 4 rows each
    const int tn = tid & 15;    // 0..15, 8 cols each

    // A-tile load indices
    const int am  = tid >> 2;         // 0..63
    const int ak4 = (tid & 3) * 4;    // 0,4,8,12
    // B-tile load indices
    const int bj  = tid >> 1;         // BT: 0..127
    const int bk8 = (tid & 1) * 8;    // BT: 0 or 8
    const int bk  = tid >> 5;         // !BT: 0..7
    const int bj4 = (tid & 31) * 4;   // !BT: 0..124

    auto loadA = [&](int kk) -> float4 {
        const int r = row0 + am;
        if (r < M) return *(const float4*)(A + (size_t)r * lda + kk + ak4);
        return make_float4(0.f, 0.f, 0.f, 0.f);
    };
    auto loadB = [&](int kk, float4& v0, float4& v1) {
        if (BT) {
            const float* bp = B + (size_t)(col0 + bj) * ldb + kk + bk8;
            v0 = *(const float4*)(bp);
            v1 = *(const float4*)(bp + 4);
        } else {
            v0 = *(const float4*)(B + (size_t)(kk + bk) * ldb + col0 + bj4);
            v1 = *(const float4*)(B + (size_t)(kk + bk + 8) * ldb + col0 + bj4);
        }
    };
    auto storeT = [&](int b, float4 va, float4 v0, float4 v1) {
        As[b][ak4 + 0][am] = va.x; As[b][ak4 + 1][am] = va.y;
        As[b][ak4 + 2][am] = va.z; As[b][ak4 + 3][am] = va.w;
        if (BT) {
            Bs[b][bk8 + 0][bj] = v0.x; Bs[b][bk8 + 1][bj] = v0.y;
            Bs[b][bk8 + 2][bj] = v0.z; Bs[b][bk8 + 3][bj] = v0.w;
            Bs[b][bk8 + 4][bj] = v1.x; Bs[b][bk8 + 5][bj] = v1.y;
            Bs[b][bk8 + 6][bj] = v1.z; Bs[b][bk8 + 7][bj] = v1.w;
        } else {
            Bs[b][bk + 0][bj4 + 0] = v0.x; Bs[b][bk + 0][bj4 + 1] = v0.y;
            Bs[b][bk + 0][bj4 + 2] = v0.z; Bs[b][bk + 0][bj4 + 3] = v0.w;
            Bs[b][bk + 8][bj4 + 0] = v1.x; Bs[b][bk + 8][bj4 + 1] = v1.y;
            Bs[b][bk + 8][bj4 + 2] = v1.z; Bs[b][bk + 8][bj4 + 3] = v1.w;
        }
    };

    float acc[4][8] = {};

    {
        float4 va = loadA(0), v0, v1;
        loadB(0, v0, v1);
        storeT(0, va, v0, v1);
    }
    __syncthreads();

    int cur = 0;
    for (int kk = 16; ; kk += 16) {
        const bool more = (kk < K);
        float4 na, n0, n1;
        if (more) { na = loadA(kk); loadB(kk, n0, n1); }

        #pragma unroll
        for (int k = 0; k < 16; k++) {
            const float4 av  = *(const float4*)&As[cur][k][tm * 4];
            const float4 bv0 = *(const float4*)&Bs[cur][k][tn * 8];
            const float4 bv1 = *(const float4*)&Bs[cur][k][tn * 8 + 4];
            const float a[4] = {av.x, av.y, av.z, av.w};
            const float b[8] = {bv0.x, bv0.y, bv0.z, bv0.w,
                                bv1.x, bv1.y, bv1.z, bv1.w};
            #pragma unroll
            for (int i = 0; i < 4; i++)
                #pragma unroll
                for (int j = 0; j < 8; j++)
                    acc[i][j] += a[i] * b[j];
        }
        if (!more) break;
        storeT(cur ^ 1, na, n0, n1);
        __syncthreads();
        cur ^= 1;
    }

    #pragma unroll
    for (int i = 0; i < 4; i++) {
        const int r = row0 + tm * 4 + i;
        if (r >= M) continue;
        const float rs = rowscale ? rowscale[r] : 1.0f;
        #pragma unroll
        for (int j = 0; j < 8; j++) {
            const int c = col0 + tn * 8 + j;
            float v = acc[i][j] * rs;
            if (mode == MODE_TANH) v = tanhf(v);
            float* p = C + (size_t)r * ldc + c;
            if (mode == MODE_ACC) *p += v;
            else                  *p = v;
        }
    }
}

// ---------------------------------------------------------------------------
// Fused dual-relation conv GEMM (BT=false, K=H=128, ldb=ldc=128), same
// register-prefetch + LDS double-buffer scheme.
//   C0[n,j] = rs0[n] * sum_k A[n,k] * B0[k,j]
//   C1[n,j] = rs1[n] * sum_k A[n,k] * B1[k,j]
// ---------------------------------------------------------------------------
__global__ __launch_bounds__(256) void gemm_conv_pair(
    const float* __restrict__ A, int lda,
    const float* __restrict__ B0, const float* __restrict__ B1,
    float* __restrict__ C0, float* __restrict__ C1,
    int M, const float* __restrict__ rs0, const float* __restrict__ rs1)
{
    __shared__ __align__(16) float As[2][16][68];
    __shared__ __align__(16) float B0s[2][16][68];
    __shared__ __align__(16) float B1s[2][16][68];

    const int row0 = blockIdx.x * 64;
    const int col0 = blockIdx.y * 64;
    const int tid  = threadIdx.x;
    const int tm = tid >> 4;
    const int tn = tid & 15;

    const int am  = tid >> 2;
    const int ak4 = (tid & 3) * 4;
    const int bk  = tid >> 4;         // 0..15
    const int bj4 = (tid & 15) * 4;   // 0..60

    auto loadA = [&](int kk) -> float4 {
        const int r = row0 + am;
        if (r < M) return *(const float4*)(A + (size_t)r * lda + kk + ak4);
        return make_float4(0.f, 0.f, 0.f, 0.f);
    };
    auto storeT = [&](int b, float4 va, float4 v0, float4 v1) {
        As[b][ak4 + 0][am] = va.x; As[b][ak4 + 1][am] = va.y;
        As[b][ak4 + 2][am] = va.z; As[b][ak4 + 3][am] = va.w;
        B0s[b][bk][bj4 + 0] = v0.x; B0s[b][bk][bj4 + 1] = v0.y;
        B0s[b][bk][bj4 + 2] = v0.z; B0s[b][bk][bj4 + 3] = v0.w;
        B1s[b][bk][bj4 + 0] = v1.x; B1s[b][bk][bj4 + 1] = v1.y;
        B1s[b][bk][bj4 + 2] = v1.z; B1s[b][bk][bj4 + 3] = v1.w;
    };

    float acc0[4][4] = {};
    float acc1[4][4] = {};

    {
        float4 va = loadA(0);
        float4 v0 = *(const float4*)(B0 + (size_t)bk * H_ + col0 + bj4);
        float4 v1 = *(const float4*)(B1 + (size_t)bk * H_ + col0 + bj4);
        storeT(0, va, v0, v1);
    }
    __syncthreads();

    int cur = 0;
    for (int kk = 16; ; kk += 16) {
        const bool more = (kk < H_);
        float4 na, n0, n1;
        if (more) {
            na = loadA(kk);
            n0 = *(const float4*)(B0 + (size_t)(kk + bk) * H_ + col0 + bj4);
            n1 = *(const float4*)(B1 + (size_t)(kk + bk) * H_ + col0 + bj4);
        }

        #pragma unroll
        for (int k = 0; k < 16; k++) {
            const float4 av  = *(const float4*)&As[cur][k][tm * 4];
            const float4 bv0 = *(const float4*)&B0s[cur][k][tn * 4];
            const float4 bv1 = *(const float4*)&B1s[cur][k][tn * 4];
            const float a[4]  = {av.x, av.y, av.z, av.w};
            const float b0[4] = {bv0.x, bv0.y, bv0.z, bv0.w};
            const float b1v[4] = {bv1.x, bv1.y, bv1.z, bv1.w};
            #pragma unroll
            for (int i = 0; i < 4; i++)
                #pragma unroll
                for (int j = 0; j < 4; j++) {
                    acc0[i][j] += a[i] * b0[j];
                    acc1[i][j] += a[i] * b1v[j];
                }
        }
        if (!more) break;
        storeT(cur ^ 1, na, n0, n1);
        __syncthreads();
        cur ^= 1;
    }

    #pragma unroll
    for (int i = 0; i < 4; i++) {
        const int r = row0 + tm * 4 + i;
        if (r >= M) continue;
        const float s0 = rs0[r];
        const float s1 = rs1[r];
        #pragma unroll
        for (int j = 0; j < 4; j++) {
            const int c = col0 + tn * 4 + j;
            C0[(size_t)r * H_ + c] = acc0[i][j] * s0;
            C1[(size_t)r * H_ + c] = acc1[i][j] * s1;
        }
    }
}

// ---------------------------------------------------------------------------
// Zero ints
// ---------------------------------------------------------------------------
__global__ __launch_bounds__(256) void zero_i(int* __restrict__ p, int n)
{
    int t = blockIdx.x * 256 + threadIdx.x;
    if (t < n) p[t] = 0;
}

// ---------------------------------------------------------------------------
// Degree counting: eb is the contiguous (R,2,E) int block for this sign.
// cnt layout: [which = r*2 + (0=src/out,1=dst/in)] x N
// ---------------------------------------------------------------------------
__global__ __launch_bounds__(256) void count_deg(const int* __restrict__ eb,
                                                 int* __restrict__ cnt, int total)
{
    int t = blockIdx.x * 256 + threadIdx.x;
    if (t >= total) return;
    int which = t / E_;
    atomicAdd(&cnt[which * N_ + eb[t]], 1);
}

// dscale[i] = rsqrt(max(cnt[i],1))
__global__ __launch_bounds__(256) void deg_finalize(const int* __restrict__ cnt,
                                                    float* __restrict__ dscale, int n)
{
    int t = blockIdx.x * 256 + threadIdx.x;
    if (t < n) {
        int v = cnt[t];
        dscale[t] = rsqrtf((float)(v < 1 ? 1 : v));
    }
}

// ---------------------------------------------------------------------------
// 3-phase parallel exclusive scan of in-degree counts -> CSR offsets+cursor.
// ---------------------------------------------------------------------------
constexpr int SCAN_NB = (N_ + 255) / 256;   // 196 blocks per relation

// phase 1: per-256-element block sums. grid (SCAN_NB, 2)
__global__ __launch_bounds__(256) void scan_p1(const int* __restrict__ cnt,
                                               int* __restrict__ bsums)
{
    const int r = blockIdx.y;
    const int* in = cnt + (size_t)(2 * r + 1) * N_;
    const int i = blockIdx.x * 256 + threadIdx.x;
    int v = (i < N_) ? in[i] : 0;
    #pragma unroll
    for (int off = 32; off > 0; off >>= 1) v += __shfl_xor(v, off);
    __shared__ int ws[4];
    if ((threadIdx.x & 63) == 0) ws[threadIdx.x >> 6] = v;
    __syncthreads();
    if (threadIdx.x == 0)
        bsums[r * SCAN_NB + blockIdx.x] = ws[0] + ws[1] + ws[2] + ws[3];
}

// phase 2: exclusive scan of the SCAN_NB block sums. grid (2)
__global__ __launch_bounds__(256) void scan_p2(int* __restrict__ bsums)
{
    __shared__ int sh[256];
    const int r = blockIdx.x;
    const int t = threadIdx.x;
    int v = (t < SCAN_NB) ? bsums[r * SCAN_NB + t] : 0;
    sh[t] = v;
    __syncthreads();
    #pragma unroll
    for (int d = 1; d < 256; d <<= 1) {
        int u = (t >= d) ? sh[t - d] : 0;
        __syncthreads();
        sh[t] += u;
        __syncthreads();
    }
    if (t < SCAN_NB) bsums[r * SCAN_NB + t] = sh[t] - v;   // exclusive
}

// phase 3: block-local exclusive scan + block prefix -> offs, cursor.
__global__ __launch_bounds__(256) void scan_p3(const int* __restrict__ cnt,
                                               const int* __restrict__ bsums,
                                               int* __restrict__ offs,
                                               int* __restrict__ cursor)
{
    __shared__ int sh[256];
    const int r = blockIdx.y;
    const int* in = cnt + (size_t)(2 * r + 1) * N_;
    int* out = offs + (size_t)r * (N_ + 1);
    int* cur = cursor + (size_t)r * N_;
    const int i = blockIdx.x * 256 + threadIdx.x;
    const int t = threadIdx.x;
    int v = (i < N_) ? in[i] : 0;
    sh[t] = v;
    __syncthreads();
    #pragma unroll
    for (int d = 1; d < 256; d <<= 1) {
        int u = (t >= d) ? sh[t - d] : 0;
        __syncthreads();
        sh[t] += u;
        __syncthreads();
    }
    const int excl = sh[t] - v + bsums[r * SCAN_NB + blockIdx.x];
    if (i < N_) { out[i] = excl; cur[i] = excl; }
    if (i == 0) out[N_] = E_;   // every edge has a dst -> total == E_
}

// csr[r*E + pos] = src, bucketed by dst
__global__ __launch_bounds__(256) void csr_fill(const int* __restrict__ eb,
                                                int* __restrict__ cursor,
                                                int* __restrict__ csr, int total)
{
    int t = blockIdx.x * 256 + threadIdx.x;
    if (t >= total) return;
    int r = (t >= E_) ? 1 : 0;
    int e = t - r * E_;
    int s = eb[(r * 2 + 0) * E_ + e];
    int d = eb[(r * 2 + 1) * E_ + e];
    int pos = atomicAdd(&cursor[r * N_ + d], 1);
    csr[(size_t)r * E_ + pos] = s;
}

// ---------------------------------------------------------------------------
// Gather helper: sum m[csr[k]] rows over [b,e), unrolled x4 (R1-verified
// depth; x8 was neutral in R4 -- compiler reschedules deeper pipelines away).
// ---------------------------------------------------------------------------
__device__ __forceinline__ void gather_rel(const float2* __restrict__ m,
                                           const int* __restrict__ csr,
                                           int b, int e, int lane, float2& acc)
{
    int k = b;
    for (; k + 4 <= e; k += 4) {
        const int s0 = csr[k + 0];
        const int s1 = csr[k + 1];
        const int s2 = csr[k + 2];
        const int s3 = csr[k + 3];
        const float2 v0 = m[(size_t)s0 * 64 + lane];
        const float2 v1 = m[(size_t)s1 * 64 + lane];
        const float2 v2 = m[(size_t)s2 * 64 + lane];
        const float2 v3 = m[(size_t)s3 * 64 + lane];
        acc.x += (v0.x + v1.x) + (v2.x + v3.x);
        acc.y += (v0.y + v1.y) + (v2.y + v3.y);
    }
    for (; k < e; k++) {
        const int s = csr[k];
        const float2 v = m[(size_t)s * 64 + lane];
        acc.x += v.x; acc.y += v.y;
    }
}

// ---------------------------------------------------------------------------
// Fused: CSR pull (both relations) + GCN finalize + relation attention.
// One wave per node; lane l holds columns {2l, 2l+1} as a float2.
// 1024-thread blocks, 2 blocks/CU = 32 waves/CU.
// Matvec change vs R4: h0/h1 staged rows are read as float4 (broadcast
// ds_read_b128) instead of scalar floats -- cuts the per-node DS-pipe
// instruction count from ~384 to ~192 (the broadcast reads were half the
// LDS issue traffic while moving 4 B each).
// ---------------------------------------------------------------------------
__global__ __launch_bounds__(1024, 8) void pull_attn(
    const float2* __restrict__ m0, const float2* __restrict__ m1,
    const int* __restrict__ offs0, const int* __restrict__ csr0,
    const int* __restrict__ offs1, const int* __restrict__ csr1,
    const float* __restrict__ si0, const float* __restrict__ si1,
    const float* __restrict__ bias0, const float* __restrict__ bias1,
    const float* __restrict__ W1, const float* __restrict__ b1,
    const float* __restrict__ w2, float2* __restrict__ outb, int n)
{
    __shared__ float W1s[H_ * Q_];                       // 32 KiB, [i*64 + q]
    __shared__ __align__(16) float2 hsS[16][2][Q_];      // per-wave staging
    __shared__ float b1s[Q_], w2s[Q_], bAs[H_], bBs[H_];

    for (int i = threadIdx.x; i < H_ * Q_; i += 1024) W1s[i] = W1[i];
    if (threadIdx.x < Q_) { b1s[threadIdx.x] = b1[threadIdx.x]; w2s[threadIdx.x] = w2[threadIdx.x]; }
    {
        const int t = (int)threadIdx.x - Q_;
        if (t >= 0 && t < H_) bAs[t] = bias0[t];
        const int u = (int)threadIdx.x - Q_ - H_;
        if (u >= 0 && u < H_) bBs[u] = bias1[u];
    }
    __syncthreads();   // weights staged; the ONLY block barrier

    const int lane = threadIdx.x & 63;
    const int wv   = threadIdx.x >> 6;
    int node = (blockIdx.x * 1024 + threadIdx.x) >> 6;
    node = __builtin_amdgcn_readfirstlane(node);   // wave-uniform -> scalar loads

    float2 hs0 = make_float2(0.f, 0.f), hs1 = hs0;

    if (node < n) {
        float2 a0 = make_float2(0.f, 0.f), a1 = a0;
        const int b0  = offs0[node], e0 = offs0[node + 1];
        const int b1i = offs1[node], e1 = offs1[node + 1];
        gather_rel(m0, csr0, b0,  e0, lane, a0);
        gather_rel(m1, csr1, b1i, e1, lane, a1);

        const float sc0 = si0[node], sc1 = si1[node];
        hs0.x = a0.x * sc0 + bAs[2 * lane];
        hs0.y = a0.y * sc0 + bAs[2 * lane + 1];
        hs1.x = a1.x * sc1 + bBs[2 * lane];
        hs1.y = a1.y * sc1 + bBs[2 * lane + 1];
        hsS[wv][0][lane] = hs0;
        hsS[wv][1][lane] = hs1;
    }

    // Wave-local publish of hsS: lanes are lockstep within a wave; draining
    // lgkmcnt makes every lane's ds_write visible to every lane's ds_read.
    __asm__ volatile("s_waitcnt lgkmcnt(0)" ::: "memory");
    __builtin_amdgcn_sched_barrier(0);

    if (node < n) {
        const float4* h0p4 = (const float4*)&hsS[wv][0][0];   // 32 float4
        const float4* h1p4 = (const float4*)&hsS[wv][1][0];
        float t0 = b1s[lane], t1 = b1s[lane];
        #pragma unroll 8
        for (int i4 = 0; i4 < 32; i4++) {
            const float4 h0v = h0p4[i4];
            const float4 h1v = h1p4[i4];
            const float wa = W1s[(i4 * 4 + 0) * Q_ + lane];
            const float wb = W1s[(i4 * 4 + 1) * Q_ + lane];
            const float wc = W1s[(i4 * 4 + 2) * Q_ + lane];
            const float wd = W1s[(i4 * 4 + 3) * Q_ + lane];
            t0 += h0v.x * wa + h0v.y * wb + h0v.z * wc + h0v.w * wd;
            t1 += h1v.x * wa + h1v.y * wb + h1v.z * wc + h1v.w * wd;
        }
        float s0 = tanhf(t0) * w2s[lane];
        float s1 = tanhf(t1) * w2s[lane];
        #pragma unroll
        for (int off = 32; off > 0; off >>= 1) {
            s0 += __shfl_xor(s0, off);
            s1 += __shfl_xor(s1, off);
        }
        const float mx = fmaxf(s0, s1);
        const float e0v = expf(s0 - mx), e1v = expf(s1 - mx);
        const float a0 = e0v / (e0v + e1v), a1 = 1.0f - a0;

        float2 o;
        o.x = a0 * hs0.x + a1 * hs1.x;
        o.y = a0 * hs0.y + a1 * hs1.y;
        outb[(size_t)node * 64 + lane] = o;
    }
}

// ---------------------------------------------------------------------------
// Orchestration
// ---------------------------------------------------------------------------
extern "C" void kernel_launch(void* const* d_in, const int* in_sizes, int n_in,
                              void* d_out, int out_size, void* d_ws, size_t ws_size,
                              hipStream_t stream)
{
    const float* x_attr = (const float*)d_in[0];
    const float* x_stru = (const float*)d_in[1];
    const int*   e_attr = (const int*)d_in[2];
    const int*   e_stru = (const int*)d_in[3];
    const float* Wf     = (const float*)d_in[4];
    const float* convW  = (const float*)d_in[5];
    const float* convB  = (const float*)d_in[6];
    const float* aW1    = (const float*)d_in[7];
    const float* aB1    = (const float*)d_in[8];
    const float* aW2    = (const float*)d_in[9];
    const float* Wc     = (const float*)d_in[10];
    float*       out    = (float*)d_out;
    float*       ws     = (float*)d_ws;

    const size_t NH = (size_t)N_ * H_;
    float* A  = ws;            // h0, later h2
    float* Bb = ws + 1 * NH;   // h1, later hA
    float* C  = ws + 2 * NH;   // m0
    float* D  = ws + 3 * NH;   // m1
    float* dscale = ws + 4 * NH;                    // 4N floats [out0,in0,out1,in1]
    int*   ibase  = (int*)(dscale + 4 * N_);
    int*   cnt    = ibase;                          // 4N ints
    int*   offs   = ibase + 4 * N_;                 // 2*(N+1)
    int*   csr    = offs + 2 * (N_ + 1);            // 2*E
    int*   cursor = csr + 2 * E_;                   // 2*N
    int*   bsums  = cursor + 2 * N_;                // 2*SCAN_NB

    const int GX = (N_ + 63) / 64;
    const dim3 GGEMM(GX, 1);                        // 64x128 tiles, full width
    const dim3 GCONV(GX, 2);                        // conv_pair: 64x64 tiles
    const dim3 GSCAN(SCAN_NB, 2);
    const int PA_B = (N_ * 64) / 1024;              // pull_attn blocks, exact

    for (int run = 0; run < 4; run++) {
        const int sign = run >> 1;
        const float* x = (run & 1) ? x_stru : x_attr;
        const int* eb = ((run & 1) ? e_stru : e_attr) + (size_t)sign * (R_ * 2 * E_);
        float* y = out + (size_t)run * NH;
        const float* WcS = Wc + (size_t)sign * H_ * 3 * H_;

        // --- degrees + CSR build (once per run, reused by all 3 layers) ---
        zero_i<<<(4 * N_ + 255) / 256, 256, 0, stream>>>(cnt, 4 * N_);
        count_deg<<<(4 * E_ + 255) / 256, 256, 0, stream>>>(eb, cnt, 4 * E_);
        deg_finalize<<<(4 * N_ + 255) / 256, 256, 0, stream>>>(cnt, dscale, 4 * N_);
        scan_p1<<<GSCAN, 256, 0, stream>>>(cnt, bsums);
        scan_p2<<<2, 256, 0, stream>>>(bsums);
        scan_p3<<<GSCAN, 256, 0, stream>>>(cnt, bsums, offs, cursor);
        csr_fill<<<(2 * E_ + 255) / 256, 256, 0, stream>>>(eb, cursor, csr, 2 * E_);

        // --- h0 = tanh(x @ Wf^T) ---
        gemm_kernel<true><<<GGEMM, 256, 0, stream>>>(
            x, F_, Wf + (size_t)sign * H_ * F_, F_, A, H_, N_, F_, nullptr, MODE_TANH);

        // --- y = h0 @ Wc[:, 0:H]^T ---
        gemm_kernel<true><<<GGEMM, 256, 0, stream>>>(
            A, H_, WcS, 3 * H_, y, H_, N_, H_, nullptr, MODE_STORE);

        // --- heterogeneous layer: fused dual-relation GEMM + pull/attention ---
        auto het = [&](const float* h_in, int l, float* outb) {
            const size_t lo = (size_t)(sign * L_ + l);
            gemm_conv_pair<<<GCONV, 256, 0, stream>>>(
                h_in, H_,
                convW + (lo * R_ + 0) * H_ * H_,
                convW + (lo * R_ + 1) * H_ * H_,
                C, D, N_,
                dscale + 0 * N_, dscale + 2 * N_);
            pull_attn<<<PA_B, 1024, 0, stream>>>(
                (const float2*)C, (const float2*)D,
                offs, csr, offs + (N_ + 1), csr + E_,
                dscale + N_, dscale + 3 * N_,
                convB + (lo * R_ + 0) * H_, convB + (lo * R_ + 1) * H_,
                aW1 + lo * H_ * Q_, aB1 + lo * Q_, aW2 + lo * Q_,
                (float2*)outb, N_);
        };

        // --- h1 = het(h0, layer 1); y += h1 @ Wc[:, H:2H]^T ---
        het(A, 1, Bb);
        gemm_kernel<true><<<GGEMM, 256, 0, stream>>>(
            Bb, H_, WcS + H_, 3 * H_, y, H_, N_, H_, nullptr, MODE_ACC);

        // --- hA = het(h0, layer 0) (h1 consumed, reuse Bb) ---
        het(A, 0, Bb);

        // --- h2 = het(hA, layer 1) -> A (h0 dead); y += h2 @ Wc[:, 2H:3H]^T ---
        het(Bb, 1, A);
        gemm_kernel<true><<<GGEMM, 256, 0, stream>>>(
            A, H_, WcS + 2 * H_, 3 * H_, y, H_, N_, H_, nullptr, MODE_ACC);
    }
}